// Round 16
// baseline (562.200 us; speedup 1.0000x reference)
//
#include <hip/hip_runtime.h>
#include <hip/hip_fp16.h>
#include <math.h>

// Reference: bev (1024,1,120,120) fp32 -> out (1024,120) fp32.
// R22 green @557us: Goertzel compaction (488 thr in 7.6 waves) + NT=1024.
// VALU 75%, LDS ~72% (conflicts 1.298e8), occupancy 47.7%, 1 blk/CU.
// R20/R21 ILP pipelining NULL (compiler already optimal); R16-R18 conflict
// layouts REFUTED (stochastic scatter, R15 8B texel optimal).
// R23 = BANDED t-WINDOW, fixing R13's two failure modes:
//  (1) wave-max trips: chord W(s)=W(-s) -> band the lanes. Wave A of each
//      128-thread slot takes OUTER s {0..31, 88..119} (short windows), wave
//      B INNER {32..87} (full windows). s = skl<32? skl : skl<64? 151-skl
//      : skl-32 (bijective). Outer wave at diagonal angles: ~96 vs 120
//      trips; axis angles 0 saved; mean ~-7% radon VALU, more on DS
//      (per-lane exec masking skips reads).
//  (2) bit-identity: skip only WHOLE 8-sample groups outside [t0,t1]
//      (tg in [t0>>3, t1>>3]); skipped groups contributed exact +0.0
//      (all-pad samples are exact zeros; clamps retained -> window is a
//      trip-count cut, never a correctness dependency). Static unroll kept;
//      tv = 8*tg-59.5+u exact -> same fp values, same order.
// Canary: absmax exactly 4.882812e-4.
#define NPIX  120
#define NS    120
#define NK    61             // independent bins 0..60; 61..119 mirrored
#define HSTR  123            // H cols: x = 0..122 (pads at 0, 121, 122)
#define HROWS 123            // H rows: y = 0..122 (pads at 0, 121, 122)
#define CHUNK 8              // angles in flight
#define NCHUNK 15            // 120 / 8
#define NT    1024           // 16 waves
#define NGO   488            // 8 slots x 61 bins, compacted Goertzel threads

#if __has_builtin(__builtin_amdgcn_fractf)
#define FRACTF(x) __builtin_amdgcn_fractf(x)
#else
#define FRACTF(x) ((x) - floorf(x))
#endif
#if __has_builtin(__builtin_amdgcn_rcpf)
#define RCPF(x) __builtin_amdgcn_rcpf(x)
#else
#define RCPF(x) (1.0f / (x))
#endif

__device__ __forceinline__ __half2 lo_h2(uint2 q) { return *reinterpret_cast<__half2*>(&q.x); }
__device__ __forceinline__ __half2 hi_h2(uint2 q) { return *reinterpret_cast<__half2*>(&q.y); }

// LDS: H 123*123*8 (121,032) + schunk dbl 2*8*120*16 (30,720) + outAcc 976
//    + invN 16 = 152,744 B -> 1 block/CU, 16 waves.

__global__ void ring_fused(const float* __restrict__ bev,
                           float* __restrict__ out,
                           int B) {
    __shared__ uint2  H[HROWS * HSTR];       // (A,B,C,D) 4xfp16 padded image
    __shared__ float4 schunk[2][CHUNK * NS]; // double-buffered sinogram rows
    __shared__ float4 outAcc[NK];
    __shared__ float  invN[4];               // per-image 1/norm (scalar stores)

    const int tid = threadIdx.x;          // 0..1023
    const int b0  = blockIdx.x * 4;       // first image of the quad
    const int al  = tid >> 7;             // radon angle slot 0..7 (128 thr/slot)
    const int skl = tid & 127;            // radon lane index (active if <120)
    // banded s permutation: wave A (skl<64) outer band, wave B inner band
    const int s_r = (skl < 32) ? skl : ((skl < 64) ? (151 - skl) : (skl - 32));
    const int alg = tid / NK;             // Goertzel slot (compacted, tid<488)
    const int kg  = tid - alg * NK;       // Goertzel bin 0..60
    if (b0 >= B) return;

    // ---- stage: build H from 4 images (each 8B word owned by 1 thread) -----
    const float* s0 = bev + (size_t)b0 * (NPIX * NPIX);
    const float* s1 = (b0 + 1 < B) ? bev + (size_t)(b0 + 1) * (NPIX * NPIX) : s0;
    const float* s2 = (b0 + 2 < B) ? bev + (size_t)(b0 + 2) * (NPIX * NPIX) : s0;
    const float* s3 = (b0 + 3 < B) ? bev + (size_t)(b0 + 3) * (NPIX * NPIX) : s0;
    for (int i = tid; i < HROWS * HSTR; i += NT) {
        int y = i / HSTR, x = i - y * HSTR;
        float va = 0.f, vb = 0.f, vc = 0.f, vd = 0.f;
        int gx = x - 1, gy = y - 1;
        if (gx >= 0 && gx < NPIX && gy >= 0 && gy < NPIX) {
            int o = gy * NPIX + gx;
            va = s0[o]; vb = s1[o]; vc = s2[o]; vd = s3[o];
        }
        __half2 ab = __floats2half2_rn(va, vb);
        __half2 cd = __floats2half2_rn(vc, vd);
        H[i] = make_uint2(*reinterpret_cast<unsigned*>(&ab),
                          *reinterpret_cast<unsigned*>(&cd));
    }
    __syncthreads();

    // ---- per-thread Goertzel constant (bin kg, used where tid < 488) -------
    const float coef = 2.f * cosf((float)kg * 0.052359877559829887f);  // 2cos(pi k/60)
    const float sgn  = (kg & 1) ? -1.f : 1.f;
    const double STEP = 6.283185307179586 / 119.0;   // linspace(0,2pi,120) step
    float acc0 = 0.f, acc1 = 0.f, acc2 = 0.f, acc3 = 0.f;

    for (int ch = 0; ch < NCHUNK; ++ch) {
        float4* buf = schunk[ch & 1];
        // ---- radon: sinogram[a = ch*8+al][s = s_r] for FOUR images ---------
        if (skl < NS) {
            int a = ch * CHUNK + al;
            float theta = (float)((double)a * STEP);
            float st = sinf(theta), ct = cosf(theta);
            float sf  = (float)s_r - 59.5f;
            float Ax  = fmaf(sf, ct, 60.5f);   // padded px at tv=0
            float Ay  = fmaf(sf, st, 60.5f);   // padded py at tv=0
            float nst = -st;

            // t-window (R13-proven math): superset of nonzero support.
            // px(t) = Ax0 + t*nst etc.; margins (-1.5, 123) absorb rcp error.
            float Ax0 = fmaf(-59.5f, nst, Ax);
            float Ay0 = fmaf(-59.5f, ct,  Ay);
            float tlo = 0.f, thi = 119.f;
            if (fabsf(nst) > 1e-5f) {
                float r  = RCPF(nst);
                float e1 = (-1.5f - Ax0) * r;
                float e2 = (123.f - Ax0) * r;
                tlo = fmaxf(tlo, fminf(e1, e2));
                thi = fminf(thi, fmaxf(e1, e2));
            }
            if (fabsf(ct) > 1e-5f) {
                float r  = RCPF(ct);
                float e1 = (-1.5f - Ay0) * r;
                float e2 = (123.f - Ay0) * r;
                tlo = fmaxf(tlo, fminf(e1, e2));
                thi = fminf(thi, fmaxf(e1, e2));
            }
            int t0 = (int)fmaxf(tlo, 0.f);                  // start early = safe
            int t1 = min(119, (int)fminf(thi, 119.f) + 1);  // end late = safe
            int g0 = t0 >> 3, g1 = t1 >> 3;                 // whole groups only

            const __half2 z2 = __float2half2_rn(0.f);
            float aA = 0.f, aB = 0.f, aC = 0.f, aD = 0.f;  // fp32 group sums
            for (int tg = g0; tg <= g1; ++tg) {        // skipped groups = +0.0
                __half2 sAB0 = z2, sAB1 = z2, sCD0 = z2, sCD1 = z2;
                float tv = fmaf(8.f, (float)tg, -59.5f);   // exact, same as R22
                #pragma unroll
                for (int u = 0; u < 8; ++u) {
                    float px = fmaf(tv, nst, Ax);
                    float py = fmaf(tv, ct,  Ay);
                    float cx = fminf(fmaxf(px, 0.f), 121.5f);  // v_med3
                    float cy = fminf(fmaxf(py, 0.f), 121.5f);
                    int   ix = (int)cx;                        // trunc = floor
                    int   iy = (int)cy;
                    float wx = FRACTF(cx);                     // cx - floor(cx)
                    float wy = FRACTF(cy);
                    int   ai = __mul24(iy, HSTR) + ix;
                    uint2 q00 = H[ai];                         // ds_read2_b64 0/1
                    uint2 q01 = H[ai + 1];
                    uint2 q10 = H[ai + HSTR];                  // ds_read2_b64 123/124
                    uint2 q11 = H[ai + HSTR + 1];
                    __half2 wx2 = __float2half2_rn(wx);
                    __half2 wy2 = __float2half2_rn(wy);
                    __half2 abT = __hfma2(wx2, __hsub2(lo_h2(q01), lo_h2(q00)), lo_h2(q00));
                    __half2 abB = __hfma2(wx2, __hsub2(lo_h2(q11), lo_h2(q10)), lo_h2(q10));
                    __half2 abV = __hfma2(wy2, __hsub2(abB, abT), abT);
                    __half2 cdT = __hfma2(wx2, __hsub2(hi_h2(q01), hi_h2(q00)), hi_h2(q00));
                    __half2 cdB = __hfma2(wx2, __hsub2(hi_h2(q11), hi_h2(q10)), hi_h2(q10));
                    __half2 cdV = __hfma2(wy2, __hsub2(cdB, cdT), cdT);
                    if (u & 1) { sAB1 = __hadd2(sAB1, abV); sCD1 = __hadd2(sCD1, cdV); }
                    else       { sAB0 = __hadd2(sAB0, abV); sCD0 = __hadd2(sCD0, cdV); }
                    tv += 1.f;
                }
                __half2 sAB = __hadd2(sAB0, sAB1);   // group sum <= 8 in fp16
                __half2 sCD = __hadd2(sCD0, sCD1);
                aA += __low2float(sAB);  aB += __high2float(sAB);
                aC += __low2float(sCD);  aD += __high2float(sCD);
            }
            buf[al * NS + s_r] = make_float4(aA, aB, aC, aD);
        }
        __syncthreads();

        // ---- Goertzel: |F[kg]| of row alg, 4 images (compacted, tid<488) ---
        // (no trailing barrier: next chunk writes the OTHER schunk buffer;
        //  reuse of THIS buffer in chunk ch+2 is fenced by ch+1's barrier)
        if (tid < NGO) {
            const float4* row = buf + alg * NS;
            float u1a = 0.f, u2a = 0.f, u1b = 0.f, u2b = 0.f;
            float u1c = 0.f, u2c = 0.f, u1d = 0.f, u2d = 0.f;
            #pragma unroll 4
            for (int s = 0; s < 60; ++s) {
                float4 lo = row[s];            // near-broadcast ds_read_b128
                float4 hi = row[s + 60];
                float wa = fmaf(sgn, hi.x, lo.x);
                float wb = fmaf(sgn, hi.y, lo.y);
                float wc = fmaf(sgn, hi.z, lo.z);
                float wd = fmaf(sgn, hi.w, lo.w);
                float va = fmaf(coef, u1a, wa - u2a); u2a = u1a; u1a = va;
                float vb = fmaf(coef, u1b, wb - u2b); u2b = u1b; u1b = vb;
                float vc = fmaf(coef, u1c, wc - u2c); u2c = u1c; u1c = vc;
                float vd = fmaf(coef, u1d, wd - u2d); u2d = u1d; u1d = vd;
            }
            float pa = fmaf(u1a, u1a, fmaf(u2a, u2a, -coef * u1a * u2a));
            float pb = fmaf(u1b, u1b, fmaf(u2b, u2b, -coef * u1b * u2b));
            float pc = fmaf(u1c, u1c, fmaf(u2c, u2c, -coef * u1c * u2c));
            float pd = fmaf(u1d, u1d, fmaf(u2d, u2d, -coef * u1d * u2d));
            pa = fmaxf(pa, 0.f); pb = fmaxf(pb, 0.f);
            pc = fmaxf(pc, 0.f); pd = fmaxf(pd, 0.f);
            acc0 += sqrtf(fmaf(pa, (1.f / 120.f), 1e-15f));  // ortho + EPS_FFT
            acc1 += sqrtf(fmaf(pb, (1.f / 120.f), 1e-15f));
            acc2 += sqrtf(fmaf(pc, (1.f / 120.f), 1e-15f));
            acc3 += sqrtf(fmaf(pd, (1.f / 120.f), 1e-15f));
        }
    }
    __syncthreads();   // all Goertzel reads done before schunk[0] is reused

    // ---- reduce 8 slot partials per bin (deterministic) --------------------
    if (tid < NGO) schunk[0][alg * NS + kg] = make_float4(acc0, acc1, acc2, acc3);
    __syncthreads();
    if (tid < NK) {
        float sa = 0.f, sb = 0.f, sc = 0.f, sd = 0.f;
        for (int a2 = 0; a2 < CHUNK; ++a2) {
            float4 v = schunk[0][a2 * NS + tid];
            sa += v.x; sb += v.y; sc += v.z; sd += v.w;
        }
        outAcc[tid] = make_float4(sa, sb, sc, sd);
    }
    __syncthreads();

    // ---- L2 norm over the full mirrored 120-vector, one thread per image ---
    if (tid < 4) {
        float ssq = 0.f;
        for (int k = 0; k < NK; ++k) {
            float v = ((const float*)&outAcc[k])[tid];
            float wgt = (k == 0 || k == 60) ? 1.f : 2.f;
            ssq = fmaf(wgt * v, v, ssq);
        }
        invN[tid] = 1.f / fmaxf(sqrtf(ssq), 1e-12f);  // per-lane scalar store
    }
    __syncthreads();

    // ---- write fp32 output (Hermitian mirror), 4 images --------------------
    if (tid < 4 * NPIX) {
        int img = tid / NPIX;
        int j   = tid - img * NPIX;
        int k   = (j <= 60) ? j : (NPIX - j);
        int bb  = b0 + img;
        if (bb < B) {
            float v = ((const float*)&outAcc[k])[img] * invN[img];
            out[(size_t)bb * NPIX + j] = v;
        }
    }
}

extern "C" void kernel_launch(void* const* d_in, const int* in_sizes, int n_in,
                              void* d_out, int out_size, void* d_ws, size_t ws_size,
                              hipStream_t stream) {
    const float* bev = (const float*)d_in[0];
    float* out = (float*)d_out;
    int B = in_sizes[0] / (NPIX * NPIX);   // 1024
    int grid = (B + 3) / 4;                // 4 images per block
    hipLaunchKernelGGL(ring_fused, dim3(grid), dim3(NT), 0, stream, bev, out, B);
}